// Round 6
// baseline (61.586 us; speedup 1.0000x reference)
//
#include <hip/hip_runtime.h>
#include <math.h>

// F0Resonance. Settled numerics model (r1-r5): reference = jax/XLA, whose
// jnp.cumsum lowers via ReduceWindowRewriter to a TILED SCAN with base
// length B=16: reshape [32768] -> [2048,16]; inner scans are naive
// SEQUENTIAL fp32 sums of length 16; tile-sum carries are scanned
// recursively (2048 -> 128 -> 8, same scheme); one fp32 combine-add per
// level. For constant increment x this collapses to table lookups:
//   A0[i]=S_seq(i+1,x), T0=A0[15]; B1[i]=S_seq(i+1,T0), T1=B1[15];
//   B2[i]=S_seq(i+1,T1), T2=B2[15]; B3[i]=S_seq(i+1,T2)
//   P2(m)= m<0?0: fl(B2[m&15] + (m2<0?0:B3[m3]))          m3=(m>>4)-1
//   P1(m)= m<0?0: fl(B1[m&15] + P2((m>>4)-1))
//   phase(j)= fl(A0[j&15] + P1((j>>4)-1))      (j = 0-based sample index)
// Evidence: exact phase deviates 0.0354 from ref; single-round/dyadic 0.031;
// bit-exact sequential 2.0 -> deviation magnitude uniquely fits tiled scan.
// sin(exact fp32 phase): f64 mod-2pi reduction (err ~1e-11) + hw v_sin_f32
// (input in REVOLUTIONS). Compare is bf16-quantized, so ~<0.004 fp32 passes.

constexpr int NSAMP = 32768;
constexpr int NROWS = 256;   // B*E = 4*64
constexpr int NOCT  = 16;
constexpr int TPB   = 1024;

// block fma-contraction / reassociation across this fp32 value
__device__ __forceinline__ float keepf(float x) {
  asm volatile("" : "+v"(x));
  return x;
}

__global__ __launch_bounds__(TPB) void f0res_kernel(
    const float* __restrict__ f0_in,
    const float* __restrict__ dec_in,
    const float* __restrict__ fs_in,
    float* __restrict__ out)
{
  const int row = blockIdx.x;
  const int t   = threadIdx.x;

  // per-octave tables: [0..15]=A0, [16..31]=B1, [32..47]=B2, [48..55]=B3
  __shared__ float s_tab[NOCT][64];
  __shared__ float s_red[TPB / 64];

  // ---- fp32 scalar chain (replicates reference roundings) ----
  const float f0a = fabsf(f0_in[row]);
  const float dcc = dec_in[row];
  const float fsv = fs_in[row];

  const float MIN_F = (float)(20.0 / 11025.0);
  const float RNG_F = (float)(3000.0 / 11025.0 - 20.0 / 11025.0);
  const float c1    = keepf(f0a * RNG_F);
  const float c2    = keepf(MIN_F + c1);        // separate add (no fma)
  const float f0ang = keepf(c2 * (float)M_PI);

  const float sg    = 1.0f / (1.0f + expf(-dcc));
  const float dvv   = 1.0f / (1.0f + expf(-sg));  // double sigmoid
  const float dvr   = keepf(dvv * 0.9405f);       // (1-0.01)*0.95
  const float decay = keepf(0.01f + dvr);         // separate add (no fma)
  const float ldv   = logf(decay + 1e-12f);

  // ---- builder: lane k-1 builds the tables of octave k ----
  if (t < NOCT) {
    const int k = t + 1;
    float fac = 0.0f;                      // 16-elem cumsum: len<=16 -> seq
    for (int j = 0; j < k; ++j) fac = keepf(fac + fsv);
    const float x = keepf(f0ang * fac);    // fl32 increment
    float* tab = s_tab[t];
    float a = 0.0f;
    for (int i = 0; i < 16; ++i) { a = keepf(a + x);  tab[i]      = a; }
    const float T0 = a;  a = 0.0f;
    for (int i = 0; i < 16; ++i) { a = keepf(a + T0); tab[16 + i] = a; }
    const float T1 = a;  a = 0.0f;
    for (int i = 0; i < 16; ++i) { a = keepf(a + T1); tab[32 + i] = a; }
    const float T2 = a;  a = 0.0f;
    for (int i = 0; i < 8;  ++i) { a = keepf(a + T2); tab[48 + i] = a; }
  }
  __syncthreads();

  // ---- main: thread t owns 0-based samples j = 32t .. 32t+31 ----
  float osc[32];
#pragma unroll
  for (int i = 0; i < 32; ++i) osc[i] = 0.0f;

  const double inv2pi = 0.15915494309189534561;

  float lc = 0.0f;
  for (int k = 0; k < NOCT; ++k) {
    lc = keepf(lc + ldv);                  // fp32 seq cumsum of log_decay
    const float w = expf(lc);              // decay^(k+1)
    const float* tab = s_tab[k];

    // carries P1(m) for the two 16-sample halves: m = 2t-1 and 2t
    float cc[2];
#pragma unroll
    for (int h = 0; h < 2; ++h) {
      const int m = 2 * t - 1 + h;
      float c = 0.0f;
      if (m >= 0) {
        c = tab[16 + (m & 15)];            // B1
        const int m2 = (m >> 4) - 1;
        if (m2 >= 0) {
          float p2 = tab[32 + (m2 & 15)];  // B2
          const int m3 = (m2 >> 4) - 1;
          if (m3 >= 0) p2 = keepf(p2 + tab[48 + m3]);  // + B3 (level-2 add)
          c = keepf(c + p2);               // level-1 combine add
        }
      }
      cc[h] = c;
    }

#pragma unroll
    for (int i = 0; i < 32; ++i) {
      const float carry = (i < 16) ? cc[0] : cc[1];
      const float p = keepf(tab[i & 15] + carry);   // level-0 combine add
      // sin of the exact fp32 phase: f64 range reduction -> hw sin (revs)
      double rev = (double)p * inv2pi;
      rev -= rint(rev);                    // frac in [-0.5, 0.5]
      const float fr = (float)rev;
      float sv;
      asm("v_sin_f32 %0, %1" : "=v"(sv) : "v"(fr));  // sin(fr * 2pi)
      const float pr = keepf(w * sv);      // mul rounds separately (ref: mul
      osc[i] = osc[i] + pr;                //  then reduce-add, k ascending)
    }
  }

  // ---- block max reduction (max is order-independent: exact) ----
  float lmax = 0.0f;
#pragma unroll
  for (int i = 0; i < 32; ++i) lmax = fmaxf(lmax, fabsf(osc[i]));
#pragma unroll
  for (int off = 32; off >= 1; off >>= 1)
    lmax = fmaxf(lmax, __shfl_xor(lmax, off, 64));
  if ((t & 63) == 0) s_red[t >> 6] = lmax;
  __syncthreads();
  float mx = s_red[0];
#pragma unroll
  for (int i = 1; i < TPB / 64; ++i) mx = fmaxf(mx, s_red[i]);
  const float mxp = keepf(mx + 1e-8f);

  // ---- IEEE fp32 division (matches ref divide), float4 stores ----
  float* op = out + (size_t)row * NSAMP + 32 * t;
#pragma unroll
  for (int g = 0; g < 8; ++g) {
    float4 v;
    v.x = osc[4 * g + 0] / mxp;
    v.y = osc[4 * g + 1] / mxp;
    v.z = osc[4 * g + 2] / mxp;
    v.w = osc[4 * g + 3] / mxp;
    *reinterpret_cast<float4*>(op + 4 * g) = v;
  }
}

extern "C" void kernel_launch(void* const* d_in, const int* in_sizes, int n_in,
                              void* d_out, int out_size, void* d_ws, size_t ws_size,
                              hipStream_t stream) {
    const float* f0  = (const float*)d_in[0];  // (4,64,1)
    const float* dcc = (const float*)d_in[1];  // decay_coefficients
    // d_in[2] = phase_offsets: computed-but-unused in the reference
    const float* fsp = (const float*)d_in[3];  // freq_spacing
    float* out = (float*)d_out;                // (4,64,32768) fp32

    f0res_kernel<<<NROWS, TPB, 0, stream>>>(f0, dcc, fsp, out);
}

// Round 8
// 48.784 us; speedup vs baseline: 1.2624x; 1.2624x over previous
//
#include <hip/hip_runtime.h>
#include <math.h>

// F0Resonance — bit-exact replication of XLA's tiled-scan cumsum (verified r6).
// jnp.cumsum lowers via ReduceWindowRewriter, base B=16: [32768]->[2048,16],
// sequential fp32 inner scans, recursive carry scan (2048->128->8), one fp32
// combine-add per level. For constant increment x:
//   A0[i]=seq(i+1,x), B1=seq(.,T0), B2=seq(.,T1), B3=seq(.,T2)
//   phase(j) = fl( A0[j&15] + P1((j>>4)-1) ),  P1(m)=fl(B1[m&15]+P2(..))
// r7 lesson: HIP's __fadd_rn/__fmul_rn are plain ops and hipcc contracts
// mul+add into FMA (fast-honor-pragmas) -> f0ang off by 1 ulp -> phase off
// by ~0.03 rad at n=32768 (the observed 3.19e-2). Pin with contract(off).
#pragma clang fp contract(off)

constexpr int NSAMP = 32768;
constexpr int NROWS = 256;   // B*E = 4*64
constexpr int NOCT  = 16;
constexpr int TPB   = 1024;

// hard barrier against any cross-statement fusion on the scalar chain
__device__ __forceinline__ float keepf(float x) {
  asm volatile("" : "+v"(x));
  return x;
}

__global__ __launch_bounds__(TPB, 4) void f0res_kernel(
    const float* __restrict__ f0_in,
    const float* __restrict__ dec_in,
    const float* __restrict__ fs_in,
    float* __restrict__ out)
{
  const int row = blockIdx.x;
  const int t   = threadIdx.x;

  __shared__ float s_tab[NOCT][64];  // [0:16)=A0 [16:32)=B1 [32:48)=B2 [48:56)=B3
  __shared__ float s_w[NOCT];
  __shared__ float s_osc[NSAMP];     // 128 KB row buffer (160 KB LDS/CU)
  __shared__ float s_red[TPB / 64];

  // ---- fp32 scalar chain (reference roundings; contraction pinned off) ----
  const float f0a = fabsf(f0_in[row]);
  const float dcc = dec_in[row];
  const float fsv = fs_in[row];

  const float MIN_F = (float)(20.0 / 11025.0);
  const float RNG_F = (float)(3000.0 / 11025.0 - 20.0 / 11025.0);
  const float c1    = keepf(f0a * RNG_F);       // fl32 mul
  const float c2    = keepf(MIN_F + c1);        // fl32 add (NOT fma)
  const float f0ang = keepf(c2 * (float)M_PI);  // fl32 mul

  const float sg    = 1.0f / (1.0f + expf(-dcc));
  const float dvv   = 1.0f / (1.0f + expf(-sg));   // double sigmoid
  const float dvr   = keepf(dvv * 0.9405f);        // (1-0.01)*0.95
  const float decay = keepf(0.01f + dvr);          // fl32 add (NOT fma)
  const float ldv   = logf(decay + 1e-12f);

  // ---- builder: lane k builds octave k's tables + weight ----
  if (t < NOCT) {
    const int k = t;
    float fac = 0.0f;
    for (int j = 0; j <= k; ++j) fac = fac + fsv;   // 16-elem seq cumsum
    const float x = keepf(f0ang * fac);
    float* tab = s_tab[k];
    float a = 0.0f;
#pragma unroll
    for (int i = 0; i < 16; ++i) { a = a + x;  tab[i]      = a; }
    const float T0 = a; a = 0.0f;
#pragma unroll
    for (int i = 0; i < 16; ++i) { a = a + T0; tab[16 + i] = a; }
    const float T1 = a; a = 0.0f;
#pragma unroll
    for (int i = 0; i < 16; ++i) { a = a + T1; tab[32 + i] = a; }
    const float T2 = a; a = 0.0f;
#pragma unroll
    for (int i = 0; i < 8;  ++i) { a = a + T2; tab[48 + i] = a; }
    float lc = 0.0f;
    for (int j = 0; j <= k; ++j) lc = lc + ldv;     // seq cumsum of log_decay
    s_w[k] = expf(lc);
  }
  __syncthreads();

  // Cody-Waite: 2pi = C1 + C2 (+~1e-10). C1 has a 7-bit mantissa, so
  // kq*C1 is exact inside the FMA for kq < 2^17 (here kq <= ~71e3).
  const float C1 = 6.28125f;
  const float C2 = (float)(6.283185307179586476925287 - 6.28125);
  const float INV2PI = (float)0.159154943091895335768883;

  float lmax = 0.0f;

  // thread t owns samples j = 32t .. 32t+31, as two 16-sample halves
#pragma unroll
  for (int h = 0; h < 2; ++h) {
    const int m = 2 * t - 1 + h;   // level-0 carry window index
    float acc[16];
#pragma unroll
    for (int i = 0; i < 16; ++i) acc[i] = 0.0f;

    for (int k = 0; k < NOCT; ++k) {
      const float* tab = s_tab[k];
      // carry P1(m): exact fp32 per the tiled scan (adds only, no fma risk)
      float carry = 0.0f;
      if (m >= 0) {
        carry = tab[16 + (m & 15)];
        const int m2 = (m >> 4) - 1;
        if (m2 >= 0) {
          float p2 = tab[32 + (m2 & 15)];
          const int m3 = (m2 >> 4) - 1;
          if (m3 >= 0) p2 = p2 + tab[48 + m3];
          carry = carry + p2;
        }
      }
      const float w = s_w[k];
      // A0 into registers (4 x ds_read_b128, uniform address -> broadcast)
      float tv[16];
      *(float4*)&tv[0]  = ((const float4*)tab)[0];
      *(float4*)&tv[4]  = ((const float4*)tab)[1];
      *(float4*)&tv[8]  = ((const float4*)tab)[2];
      *(float4*)&tv[12] = ((const float4*)tab)[3];
#pragma unroll
      for (int i = 0; i < 16; ++i) {
        const float p = tv[i] + carry;            // exact ref phase bits
        // fp32 Cody-Waite mod 2pi -> revolutions (|err| ~1e-5 rad)
        const float kq = rintf(p * INV2PI);
        float r = __builtin_fmaf(-kq, C1, p);     // exact
        r = __builtin_fmaf(-kq, C2, r);
        const float fr = r * INV2PI;
        float sv;
        asm("v_sin_f32 %0, %1" : "=v"(sv) : "v"(fr));  // sin(fr * 2pi)
        const float pr = w * sv;                  // ref: mul rounds, then add
        acc[i] = acc[i] + pr;                     // (contract off: no fma)
      }
    }
#pragma unroll
    for (int i = 0; i < 16; ++i) lmax = fmaxf(lmax, fabsf(acc[i]));
    // stage half into LDS row buffer
    float4* dst = (float4*)&s_osc[32 * t + 16 * h];
#pragma unroll
    for (int q = 0; q < 4; ++q) {
      float4 v;
      v.x = acc[4*q]; v.y = acc[4*q+1]; v.z = acc[4*q+2]; v.w = acc[4*q+3];
      dst[q] = v;
    }
  }

  // ---- block max reduction (order-independent) ----
#pragma unroll
  for (int off = 32; off >= 1; off >>= 1)
    lmax = fmaxf(lmax, __shfl_xor(lmax, off, 64));
  if ((t & 63) == 0) s_red[t >> 6] = lmax;
  __syncthreads();   // also covers s_osc
  float mx = s_red[0];
#pragma unroll
  for (int i = 1; i < TPB / 64; ++i) mx = fmaxf(mx, s_red[i]);
  const float inv = 1.0f / (mx + 1e-8f);

  // ---- pass 2: lane-contiguous LDS reads -> coalesced float4 stores ----
  float4* orow = (float4*)(out + (size_t)row * NSAMP);
  const float4* src = (const float4*)s_osc;
#pragma unroll
  for (int g = 0; g < 8; ++g) {
    float4 v = src[t + 1024 * g];
    v.x *= inv; v.y *= inv; v.z *= inv; v.w *= inv;
    orow[t + 1024 * g] = v;
  }
}

extern "C" void kernel_launch(void* const* d_in, const int* in_sizes, int n_in,
                              void* d_out, int out_size, void* d_ws, size_t ws_size,
                              hipStream_t stream) {
    const float* f0  = (const float*)d_in[0];  // (4,64,1)
    const float* dcc = (const float*)d_in[1];  // decay_coefficients
    // d_in[2] = phase_offsets: computed-but-unused in the reference
    const float* fsp = (const float*)d_in[3];  // freq_spacing
    float* out = (float*)d_out;                // (4,64,32768) fp32

    f0res_kernel<<<NROWS, TPB, 0, stream>>>(f0, dcc, fsp, out);
}